// Round 6
// baseline (191.653 us; speedup 1.0000x reference)
//
#include <hip/hip_runtime.h>

#define LROW 136   // padded LDS row stride in bf16 elements (128 + 8); 272 B rows

typedef __bf16 bf16x8  __attribute__((ext_vector_type(8)));
typedef __bf16 bf16x4v __attribute__((ext_vector_type(4)));
typedef __bf16 bf16x2v __attribute__((ext_vector_type(2)));
typedef float  f32x4   __attribute__((ext_vector_type(4)));
typedef float  f32x2   __attribute__((ext_vector_type(2)));

#define MFMA16(a, b, c) __builtin_amdgcn_mfma_f32_16x16x32_bf16((a), (b), (c), 0, 0, 0)

__device__ __forceinline__ float bflo(unsigned v) { return __uint_as_float(v << 16); }
__device__ __forceinline__ float bfhi(unsigned v) { return __uint_as_float(v & 0xffff0000u); }

__device__ __forceinline__ unsigned short f2bf_u16(float f) {
  unsigned u = __float_as_uint(f);
  u += 0x7fffu + ((u >> 16) & 1u);
  return (unsigned short)(u >> 16);
}

// ---------------------------------------------------------------------------
// Kernel 1: fold linear layers into combined weight matrices (bf16, [n][k]
// transposed layout) + folded bias vectors (f32). Bias reductions parallel
// (blocks 321-323).
//   WA = pre_W2 @ msg_W1[0:128]     WB = pre_W2 @ msg_W1[128:256]
//   WD = pre_W2 @ post_W1[128:256]  WC = msg_W2 @ post_W1[0:128]
//   WO = post_W2 @ out_W1           Wo2T = out_W2^T
//   vecs = [w1d | cAB | cP | cO]
// ---------------------------------------------------------------------------
__global__ void combine_weights(
    const float* __restrict__ pre_W2, const float* __restrict__ msg_W1,
    const float* __restrict__ msg_W2, const float* __restrict__ post_W1,
    const float* __restrict__ post_W2, const float* __restrict__ out_W1,
    const float* __restrict__ out_W2, const float* __restrict__ pre_b2,
    const float* __restrict__ msg_b1, const float* __restrict__ msg_b2,
    const float* __restrict__ post_b1, const float* __restrict__ post_b2,
    const float* __restrict__ out_b1,
    unsigned short* __restrict__ WabT, unsigned short* __restrict__ WdT,
    unsigned short* __restrict__ WcT, unsigned short* __restrict__ WoT,
    unsigned short* __restrict__ Wo2T, float* __restrict__ vecs)
{
  __shared__ float part[256];
  const int b = blockIdx.x;
  const int t = threadIdx.x;
  if (b < 320) {
    const int p  = b >> 6;
    const int kp = b & 63;
    const int k  = kp * 2 + (t >> 7);
    const int n  = t & 127;
    const float* L; const float* R; unsigned short* O;
    if (p == 0)      { L = pre_W2;  R = msg_W1;             O = WabT; }
    else if (p == 1) { L = pre_W2;  R = msg_W1 + 128*128;   O = WabT + 128*128; }
    else if (p == 2) { L = pre_W2;  R = post_W1 + 128*128;  O = WdT; }
    else if (p == 3) { L = msg_W2;  R = post_W1;            O = WcT; }
    else             { L = post_W2; R = out_W1;             O = WoT; }
    const float* Lr = L + k * 128;
    float a0 = 0.f, a1 = 0.f, a2 = 0.f, a3 = 0.f;
    #pragma unroll 8
    for (int m = 0; m < 128; m += 4) {
      a0 = fmaf(Lr[m + 0], R[(m + 0) * 128 + n], a0);
      a1 = fmaf(Lr[m + 1], R[(m + 1) * 128 + n], a1);
      a2 = fmaf(Lr[m + 2], R[(m + 2) * 128 + n], a2);
      a3 = fmaf(Lr[m + 3], R[(m + 3) * 128 + n], a3);
    }
    O[n * 128 + k] = f2bf_u16((a0 + a1) + (a2 + a3));
  } else if (b == 320) {
    for (int idx = t; idx < 16 * 128; idx += 256) {
      int o = idx >> 7, k = idx & 127;
      Wo2T[o * 128 + k] = f2bf_u16(out_W2[k * 16 + o]);
    }
    if (t < 128) vecs[t] = msg_W1[256 * 128 + t];          // w1d
  } else {
    const int n = t & 127;
    const int h = t >> 7;
    float s = 0.f;
    if (b == 321) {            // cAB = pre_b2@(W1a+W1b) + msg_b1
      #pragma unroll 8
      for (int m = h * 64; m < h * 64 + 64; ++m)
        s = fmaf(pre_b2[m], msg_W1[m * 128 + n] + msg_W1[(128 + m) * 128 + n], s);
    } else if (b == 322) {     // cP = 7*msg_b2@P1a + pre_b2@P1b + post_b1
      #pragma unroll 8
      for (int m = h * 64; m < h * 64 + 64; ++m) {
        s = fmaf(7.f * msg_b2[m], post_W1[m * 128 + n], s);
        s = fmaf(pre_b2[m], post_W1[(128 + m) * 128 + n], s);
      }
    } else {                   // cO = 8*post_b2@out_W1 + out_b1
      #pragma unroll 8
      for (int m = h * 64; m < h * 64 + 64; ++m)
        s = fmaf(8.f * post_b2[m], out_W1[m * 128 + n], s);
    }
    part[t] = s;
    __syncthreads();
    if (t < 128) {
      float r = part[t] + part[t + 128];
      if (b == 321)      vecs[128 + t] = r + msg_b1[t];
      else if (b == 322) vecs[256 + t] = r + post_b1[t];
      else               vecs[384 + t] = r + out_b1[t];
    }
  }
}

// ---------------------------------------------------------------------------
// Kernel 2: fully fused RRN. R6 redesign: one block = 4 graphs = 32 node-rows
// (was 8/64). Rationale (R5 post-mortem): kernel is latency-bound across
// barrier phases at 2.9 waves/SIMD; VALU packing was neutral. Halving the
// tile halves peak accumulators (32 acc regs) and LDS (20480 B exactly),
// allowing 6 blocks/CU via __launch_bounds__(256,6). pre_W1 staged as bf16
// to fit the staging alias under Ab.
// ---------------------------------------------------------------------------
__global__ void __launch_bounds__(256, 6) rrn_main(
    const int* __restrict__ anchors, const int* __restrict__ n_jumps,
    const float* __restrict__ positions, const int* __restrict__ colors,
    const int* __restrict__ markers, const float* __restrict__ pre_W1,
    const float* __restrict__ pre_b1,
    const __bf16* __restrict__ WabT, const __bf16* __restrict__ WdT,
    const __bf16* __restrict__ WcT, const __bf16* __restrict__ WoT,
    const __bf16* __restrict__ Wo2T, const float* __restrict__ vecs,
    const float* __restrict__ out_b2, float* __restrict__ out)
{
  __shared__ __align__(16) char smem[20480];
  // vec f32[512] @0; dist f32[256] @2048;
  // Ab bf16[32][LROW] @3072 (phase2+: A, then S in place)
  //   phase 0-1 alias: sW1b bf16[18*128] @3072, qrow f32[4*128] @7680,
  //   posL f32[64] @9728, cmk short[32] @9984 (ends 10048 < 11776)
  // h1 bf16[32][LROW] @11776 (phases 1-2); Bb after D pass;
  //   Sph bf16[16][LROW] @11776, hob @16128 (phases 5+). Total 20480.
  float*  vec  = (float*)(smem);
  float*  dist = (float*)(smem + 2048);
  __bf16* Ab   = (__bf16*)(smem + 3072);
  __bf16* sW1b = (__bf16*)(smem + 3072);
  float*  qrow = (float*)(smem + 7680);
  float*  posL = (float*)(smem + 9728);
  short*  cmk  = (short*)(smem + 9984);
  __bf16* h1   = (__bf16*)(smem + 11776);
  __bf16* Bb   = (__bf16*)(smem + 11776);
  __bf16* Sph  = (__bf16*)(smem + 11776);
  __bf16* hob  = (__bf16*)(smem + 16128);

  const int tid  = threadIdx.x;
  const int lane = tid & 63;
  const int w    = tid >> 6;      // wave 0..3
  const int l15  = lane & 15;
  const int quad = lane >> 4;
  const int colw = w * 32;        // this wave's 32-col slice
  const int g0   = blockIdx.x * 4;
  const int n0   = blockIdx.x * 32;

  // ---- phase 0: stage pre_W1 (bf16), qrow, node data, dist, vec
  for (int i = tid; i < 18 * 128; i += 256) sW1b[i] = (__bf16)pre_W1[i];
  {
    const int n = tid & 127;
    for (int g = (tid >> 7); g < 4; g += 2) {
      int a = anchors[g0 + g], nj = n_jumps[g0 + g];
      qrow[g * 128 + n] = pre_b1[n] + pre_W1[(18 + a) * 128 + n]
                        + pre_W1[(34 + nj) * 128 + n];
    }
  }
  if (tid < 64) posL[tid] = positions[n0 * 2 + tid];
  else if (tid < 96) {
    int node = tid - 64;
    cmk[node] = (short)(colors[n0 + node] | ((markers[n0 + node] - 8) << 8));
  }
  {
    int g = tid >> 6, ii = (tid >> 3) & 7, jj = tid & 7;
    const float* pa = positions + (n0 + g * 8 + ii) * 2;
    const float* pb = positions + (n0 + g * 8 + jj) * 2;
    float dx = pa[0] - pb[0], dy = pa[1] - pb[1];
    dist[tid] = sqrtf(dx * dx + dy * dy);
  }
  for (int i = tid; i < 512; i += 256) vec[i] = vecs[i];
  __syncthreads();

  // ---- phase 1: h1 = relu(feat @ pre_W1 + pre_b1), packed f32x2, LDS-only.
  //      Thread owns dim-pair p; its wave owns 8 rows.
  {
    const int p = lane * 2;
    const f32x2 z2 = {0.f, 0.f};
    unsigned vx = *(const unsigned*)&sW1b[p];
    unsigned vy = *(const unsigned*)&sW1b[128 + p];
    const f32x2 wx = {bflo(vx), bfhi(vx)};
    const f32x2 wy = {bflo(vy), bfhi(vy)};
    #pragma unroll
    for (int rr = 0; rr < 8; ++rr) {
      int r = w * 8 + rr;
      float px = posL[r * 2], py = posL[r * 2 + 1];   // wave-uniform broadcast
      int cm = cmk[r];
      int c = cm & 255, mk = cm >> 8;
      f32x2 acc = *(const f32x2*)&qrow[(r >> 3) * 128 + p];
      unsigned vc = *(const unsigned*)&sW1b[(2 + c) * 128 + p];
      unsigned vm = *(const unsigned*)&sW1b[(10 + mk) * 128 + p];
      f32x2 t = {bflo(vc) + bflo(vm), bfhi(vc) + bfhi(vm)};
      acc += t;
      f32x2 px2 = {px, px}, py2 = {py, py};
      acc = __builtin_elementwise_fma(px2, wx, acc);
      acc = __builtin_elementwise_fma(py2, wy, acc);
      acc = __builtin_elementwise_max(acc, z2);
      bf16x2v o = { (__bf16)acc.x, (__bf16)acc.y };
      *(bf16x2v*)&h1[r * LROW + p] = o;
    }
  }
  __syncthreads();

  // ---- phase 2 pass 1: [A|B] cols colw..colw+31 = h1 @ WabT (8 accs, M=32)
  f32x4 acc1[2][4];   // nt 0,1 -> A; nt 2,3 -> B
  {
    f32x4 zero = {0.f, 0.f, 0.f, 0.f};
    #pragma unroll
    for (int mt = 0; mt < 2; ++mt)
      #pragma unroll
      for (int nt = 0; nt < 4; ++nt) acc1[mt][nt] = zero;
  }
  #pragma unroll
  for (int kb = 0; kb < 128; kb += 32) {
    const int ko = kb + quad * 8;
    bf16x8 fa[2], fb[4];
    fa[0] = *(const bf16x8*)&h1[(l15) * LROW + ko];
    fa[1] = *(const bf16x8*)&h1[(16 + l15) * LROW + ko];
    fb[0] = *(const bf16x8*)&WabT[(colw + l15) * 128 + ko];
    fb[1] = *(const bf16x8*)&WabT[(colw + 16 + l15) * 128 + ko];
    fb[2] = *(const bf16x8*)&WabT[(128 + colw + l15) * 128 + ko];
    fb[3] = *(const bf16x8*)&WabT[(128 + colw + 16 + l15) * 128 + ko];
    #pragma unroll
    for (int mt = 0; mt < 2; ++mt)
      #pragma unroll
      for (int nt = 0; nt < 4; ++nt)
        acc1[mt][nt] = MFMA16(fa[mt], fb[nt], acc1[mt][nt]);
  }
  // write back A now (staging region dead since phase-1 barrier)
  #pragma unroll
  for (int mt = 0; mt < 2; ++mt)
    #pragma unroll
    for (int nt = 0; nt < 2; ++nt) {
      int col = colw + nt * 16 + l15;
      #pragma unroll
      for (int r = 0; r < 4; ++r)
        Ab[(mt * 16 + quad * 4 + r) * LROW + col] = (__bf16)acc1[mt][nt][r];
    }

  // ---- phase 2 pass 2: D cols colw..colw+31 = h1 @ WdT (4 accs, live to phase 5)
  f32x4 accD[2][2];
  {
    f32x4 zero = {0.f, 0.f, 0.f, 0.f};
    accD[0][0] = zero; accD[0][1] = zero; accD[1][0] = zero; accD[1][1] = zero;
  }
  #pragma unroll
  for (int kb = 0; kb < 128; kb += 32) {
    const int ko = kb + quad * 8;
    bf16x8 fa[2], fd[2];
    fa[0] = *(const bf16x8*)&h1[(l15) * LROW + ko];
    fa[1] = *(const bf16x8*)&h1[(16 + l15) * LROW + ko];
    fd[0] = *(const bf16x8*)&WdT[(colw + l15) * 128 + ko];
    fd[1] = *(const bf16x8*)&WdT[(colw + 16 + l15) * 128 + ko];
    #pragma unroll
    for (int mt = 0; mt < 2; ++mt) {
      accD[mt][0] = MFMA16(fa[mt], fd[0], accD[mt][0]);
      accD[mt][1] = MFMA16(fa[mt], fd[1], accD[mt][1]);
    }
  }
  __syncthreads();   // all waves done reading h1
  // write back B over the dead h1 region
  #pragma unroll
  for (int mt = 0; mt < 2; ++mt)
    #pragma unroll
    for (int nt = 2; nt < 4; ++nt) {
      int col = colw + (nt - 2) * 16 + l15;
      #pragma unroll
      for (int r = 0; r < 4; ++r)
        Bb[(mt * 16 + quad * 4 + r) * LROW + col] = (__bf16)acc1[mt][nt][r];
    }
  __syncthreads();

  // ---- phase 4: edges, packed f32x2. One wave per graph, 2 dims/thread.
  //      S[i] = sum_{j!=i} relu(A[i]+B[j]+d_ij*w1d+cAB), in place over A.
  {
    const int g   = w;
    const int nb2 = lane * 2;
    const f32x2 w0 = *(const f32x2*)&vec[nb2];
    const f32x2 c0 = *(const f32x2*)&vec[128 + nb2];
    const f32x2 z2 = {0.f, 0.f};
    f32x2 B0[8];
    #pragma unroll
    for (int j = 0; j < 8; ++j) {
      unsigned vb = *(const unsigned*)&Bb[(g * 8 + j) * LROW + nb2];
      B0[j].x = bflo(vb); B0[j].y = bfhi(vb);
    }
    #pragma unroll
    for (int i = 0; i < 8; ++i) {
      unsigned va = *(const unsigned*)&Ab[(g * 8 + i) * LROW + nb2];
      f32x2 a0 = {bflo(va), bfhi(va)};
      a0 += c0;
      f32x2 s0 = z2;
      #pragma unroll
      for (int j = 0; j < 8; ++j) {
        if (j == i) continue;
        float d = dist[g * 64 + i * 8 + j];   // wave-uniform broadcast
        f32x2 d2 = {d, d};
        f32x2 t0 = __builtin_elementwise_fma(d2, w0, B0[j]) + a0;
        t0 = __builtin_elementwise_max(t0, z2);
        s0 += t0;
      }
      bf16x2v o = { (__bf16)s0.x, (__bf16)s0.y };
      *(bf16x2v*)&Ab[(g * 8 + i) * LROW + nb2] = o;   // in-place
    }
  }
  __syncthreads();

  // ---- phase 5: ph = relu(S@Wc + D + cP); per-graph sum -> Sph rows 0..3;
  //      rows 4..15 zeroed (h1/Bb region is dead now).
  {
    unsigned* zp = (unsigned*)(Sph + 4 * LROW);
    for (int i = tid; i < (12 * LROW) / 2; i += 256) zp[i] = 0u;

    const __bf16* Sb = Ab;
    #pragma unroll
    for (int kb = 0; kb < 128; kb += 32) {
      const int ko = kb + quad * 8;
      bf16x8 fa[2], fc[2];
      fa[0] = *(const bf16x8*)&Sb[(l15) * LROW + ko];
      fa[1] = *(const bf16x8*)&Sb[(16 + l15) * LROW + ko];
      fc[0] = *(const bf16x8*)&WcT[(colw + l15) * 128 + ko];
      fc[1] = *(const bf16x8*)&WcT[(colw + 16 + l15) * 128 + ko];
      #pragma unroll
      for (int mt = 0; mt < 2; ++mt) {
        accD[mt][0] = MFMA16(fa[mt], fc[0], accD[mt][0]);
        accD[mt][1] = MFMA16(fa[mt], fc[1], accD[mt][1]);
      }
    }
    #pragma unroll
    for (int mt = 0; mt < 2; ++mt)
      #pragma unroll
      for (int dt = 0; dt < 2; ++dt) {
        int col = colw + dt * 16 + l15;
        float cp = vec[256 + col];
        f32x4 a = accD[mt][dt];
        float s = fmaxf(a[0] + cp, 0.f) + fmaxf(a[1] + cp, 0.f)
                + fmaxf(a[2] + cp, 0.f) + fmaxf(a[3] + cp, 0.f);
        s += __shfl_xor(s, 16);
        int grow = mt * 2 + (lane >= 32 ? 1 : 0);    // graph 0..3
        if ((lane & 31) < 16) Sph[grow * LROW + col] = (__bf16)s;
      }
  }
  __syncthreads();

  // ---- phase 6: ho = relu(Sph @ WO + cO)  (M=16 tile: 4 graphs + 12 zero rows)
  {
    f32x4 acco[2];
    f32x4 zero = {0.f, 0.f, 0.f, 0.f};
    acco[0] = zero; acco[1] = zero;
    #pragma unroll
    for (int kb = 0; kb < 128; kb += 32) {
      const int ko = kb + quad * 8;
      bf16x8 fa = *(const bf16x8*)&Sph[l15 * LROW + ko];
      bf16x8 fb0 = *(const bf16x8*)&WoT[(colw + l15) * 128 + ko];
      bf16x8 fb1 = *(const bf16x8*)&WoT[(colw + 16 + l15) * 128 + ko];
      acco[0] = MFMA16(fa, fb0, acco[0]);
      acco[1] = MFMA16(fa, fb1, acco[1]);
    }
    #pragma unroll
    for (int dt = 0; dt < 2; ++dt) {
      int col = colw + dt * 16 + l15;
      float co = vec[384 + col];
      #pragma unroll
      for (int r = 0; r < 4; ++r)
        hob[(quad * 4 + r) * LROW + col] = (__bf16)fmaxf(acco[dt][r] + co, 0.f);
    }
  }
  __syncthreads();

  // ---- phase 7: logits = ho @ out_W2 + out_b2  (wave 0; rows 0..3 valid)
  if (w == 0) {
    f32x4 accf = {0.f, 0.f, 0.f, 0.f};
    #pragma unroll
    for (int kb = 0; kb < 128; kb += 32) {
      const int ko = kb + quad * 8;
      bf16x8 fa  = *(const bf16x8*)&hob[l15 * LROW + ko];
      bf16x8 fbv = *(const bf16x8*)&Wo2T[l15 * 128 + ko];
      accf = MFMA16(fa, fbv, accf);
    }
    if (quad == 0) {
      float b2 = out_b2[l15];
      #pragma unroll
      for (int r = 0; r < 4; ++r)
        out[(g0 + r) * 16 + l15] = accf[r] + b2;
    }
  }
}

extern "C" void kernel_launch(void* const* d_in, const int* in_sizes, int n_in,
                              void* d_out, int out_size, void* d_ws, size_t ws_size,
                              hipStream_t stream) {
  const int*   anchors   = (const int*)d_in[0];
  const int*   n_jumps   = (const int*)d_in[1];
  const float* positions = (const float*)d_in[2];
  const int*   colors    = (const int*)d_in[3];
  const int*   markers   = (const int*)d_in[4];
  const float* pre_W1  = (const float*)d_in[5];
  const float* pre_b1  = (const float*)d_in[6];
  const float* pre_W2  = (const float*)d_in[7];
  const float* pre_b2  = (const float*)d_in[8];
  const float* msg_W1  = (const float*)d_in[9];
  const float* msg_b1  = (const float*)d_in[10];
  const float* msg_W2  = (const float*)d_in[11];
  const float* msg_b2  = (const float*)d_in[12];
  const float* post_W1 = (const float*)d_in[13];
  const float* post_b1 = (const float*)d_in[14];
  const float* post_W2 = (const float*)d_in[15];
  const float* post_b2 = (const float*)d_in[16];
  const float* out_W1  = (const float*)d_in[17];
  const float* out_b1  = (const float*)d_in[18];
  const float* out_W2  = (const float*)d_in[19];
  const float* out_b2  = (const float*)d_in[20];

  char* ws = (char*)d_ws;
  unsigned short* WabT = (unsigned short*)(ws);            // [256][128] bf16
  unsigned short* WdT  = (unsigned short*)(ws + 65536);    // [128][128]
  unsigned short* WcT  = (unsigned short*)(ws + 98304);    // [128][128]
  unsigned short* WoT  = (unsigned short*)(ws + 131072);   // [128][128]
  unsigned short* Wo2T = (unsigned short*)(ws + 163840);   // [16][128]
  float*          vecs = (float*)(ws + 167936);            // 512 f32

  const int BS = in_sizes[0];

  combine_weights<<<324, 256, 0, stream>>>(
      pre_W2, msg_W1, msg_W2, post_W1, post_W2, out_W1, out_W2,
      pre_b2, msg_b1, msg_b2, post_b1, post_b2, out_b1,
      WabT, WdT, WcT, WoT, Wo2T, vecs);

  rrn_main<<<BS / 4, 256, 0, stream>>>(
      anchors, n_jumps, positions, colors, markers, pre_W1, pre_b1,
      (const __bf16*)WabT, (const __bf16*)WdT, (const __bf16*)WcT,
      (const __bf16*)WoT, (const __bf16*)Wo2T, vecs, out_b2, (float*)d_out);
}

// Round 7
// 152.462 us; speedup vs baseline: 1.2571x; 1.2571x over previous
//
#include <hip/hip_runtime.h>

#define LROW 136   // padded LDS row stride in bf16 elements (128 + 8); 272 B rows
#define FSTR 72    // feat row stride in bf16 (64 K-cols + 8 pad); 144 B rows

typedef __bf16 bf16x8  __attribute__((ext_vector_type(8)));
typedef __bf16 bf16x2v __attribute__((ext_vector_type(2)));
typedef float  f32x4   __attribute__((ext_vector_type(4)));
typedef float  f32x2   __attribute__((ext_vector_type(2)));

#define MFMA16(a, b, c) __builtin_amdgcn_mfma_f32_16x16x32_bf16((a), (b), (c), 0, 0, 0)

__device__ __forceinline__ float bflo(unsigned v) { return __uint_as_float(v << 16); }
__device__ __forceinline__ float bfhi(unsigned v) { return __uint_as_float(v & 0xffff0000u); }

__device__ __forceinline__ unsigned short f2bf_u16(float f) {
  unsigned u = __float_as_uint(f);
  u += 0x7fffu + ((u >> 16) & 1u);
  return (unsigned short)(u >> 16);
}

// ---------------------------------------------------------------------------
// Kernel 1: fold linear layers into combined weight matrices (bf16, [n][k]
// transposed layout) + folded bias vectors (f32) + W1pT (pre_W1 transposed,
// bias folded as feature k=42, zero-padded to K=64).
//   WA = pre_W2 @ msg_W1[0:128]     WB = pre_W2 @ msg_W1[128:256]
//   WD = pre_W2 @ post_W1[128:256]  WC = msg_W2 @ post_W1[0:128]
//   WO = post_W2 @ out_W1           Wo2T = out_W2^T
//   vecs = [w1d | cAB | cP | cO]
// ---------------------------------------------------------------------------
__global__ void combine_weights(
    const float* __restrict__ pre_W1, const float* __restrict__ pre_b1,
    const float* __restrict__ pre_W2, const float* __restrict__ msg_W1,
    const float* __restrict__ msg_W2, const float* __restrict__ post_W1,
    const float* __restrict__ post_W2, const float* __restrict__ out_W1,
    const float* __restrict__ out_W2, const float* __restrict__ pre_b2,
    const float* __restrict__ msg_b1, const float* __restrict__ msg_b2,
    const float* __restrict__ post_b1, const float* __restrict__ post_b2,
    const float* __restrict__ out_b1,
    unsigned short* __restrict__ WabT, unsigned short* __restrict__ WdT,
    unsigned short* __restrict__ WcT, unsigned short* __restrict__ WoT,
    unsigned short* __restrict__ Wo2T, unsigned short* __restrict__ W1pT,
    float* __restrict__ vecs)
{
  __shared__ float part[256];
  const int b = blockIdx.x;
  const int t = threadIdx.x;
  if (b < 320) {
    const int p  = b >> 6;
    const int kp = b & 63;
    const int k  = kp * 2 + (t >> 7);
    const int n  = t & 127;
    const float* L; const float* R; unsigned short* O;
    if (p == 0)      { L = pre_W2;  R = msg_W1;             O = WabT; }
    else if (p == 1) { L = pre_W2;  R = msg_W1 + 128*128;   O = WabT + 128*128; }
    else if (p == 2) { L = pre_W2;  R = post_W1 + 128*128;  O = WdT; }
    else if (p == 3) { L = msg_W2;  R = post_W1;            O = WcT; }
    else             { L = post_W2; R = out_W1;             O = WoT; }
    const float* Lr = L + k * 128;
    float a0 = 0.f, a1 = 0.f, a2 = 0.f, a3 = 0.f;
    #pragma unroll 8
    for (int m = 0; m < 128; m += 4) {
      a0 = fmaf(Lr[m + 0], R[(m + 0) * 128 + n], a0);
      a1 = fmaf(Lr[m + 1], R[(m + 1) * 128 + n], a1);
      a2 = fmaf(Lr[m + 2], R[(m + 2) * 128 + n], a2);
      a3 = fmaf(Lr[m + 3], R[(m + 3) * 128 + n], a3);
    }
    O[n * 128 + k] = f2bf_u16((a0 + a1) + (a2 + a3));
  } else if (b == 320) {
    // Wo2T transpose, w1d copy, W1pT build
    for (int idx = t; idx < 16 * 128; idx += 256) {
      int o = idx >> 7, k = idx & 127;
      Wo2T[o * 128 + k] = f2bf_u16(out_W2[k * 16 + o]);
    }
    if (t < 128) vecs[t] = msg_W1[256 * 128 + t];          // w1d
    for (int idx = t; idx < 128 * 64; idx += 256) {
      int n = idx >> 6, k = idx & 63;
      float v = (k < 42) ? pre_W1[k * 128 + n] : (k == 42 ? pre_b1[n] : 0.f);
      W1pT[n * 64 + k] = f2bf_u16(v);
    }
  } else {
    const int n = t & 127;
    const int h = t >> 7;
    float s = 0.f;
    if (b == 321) {            // cAB = pre_b2@(W1a+W1b) + msg_b1
      #pragma unroll 8
      for (int m = h * 64; m < h * 64 + 64; ++m)
        s = fmaf(pre_b2[m], msg_W1[m * 128 + n] + msg_W1[(128 + m) * 128 + n], s);
    } else if (b == 322) {     // cP = 7*msg_b2@P1a + pre_b2@P1b + post_b1
      #pragma unroll 8
      for (int m = h * 64; m < h * 64 + 64; ++m) {
        s = fmaf(7.f * msg_b2[m], post_W1[m * 128 + n], s);
        s = fmaf(pre_b2[m], post_W1[(128 + m) * 128 + n], s);
      }
    } else {                   // cO = 8*post_b2@out_W1 + out_b1
      #pragma unroll 8
      for (int m = h * 64; m < h * 64 + 64; ++m)
        s = fmaf(8.f * post_b2[m], out_W1[m * 128 + n], s);
    }
    part[t] = s;
    __syncthreads();
    if (t < 128) {
      float r = part[t] + part[t + 128];
      if (b == 321)      vecs[128 + t] = r + msg_b1[t];
      else if (b == 322) vecs[256 + t] = r + post_b1[t];
      else               vecs[384 + t] = r + out_b1[t];
    }
  }
}

// ---------------------------------------------------------------------------
// Kernel 2: fully fused RRN. One block = 8 graphs = 64 node-rows (R5 tile --
// R6's half-tile regressed: per-block fixed cost dominates). R7: phase 0/1
// rebuilt -- sparse one-hot feature rows (bf16, K=64 padded, bias as feature)
// + h1 via MFMA against pre-transposed W1pT. Eliminates the 2300-load pre_W1
// staging and the gather-MLP VALU, the largest per-block fixed cost.
// ---------------------------------------------------------------------------
__global__ void __launch_bounds__(256, 4) rrn_main(
    const int* __restrict__ anchors, const int* __restrict__ n_jumps,
    const float* __restrict__ positions, const int* __restrict__ colors,
    const int* __restrict__ markers,
    const __bf16* __restrict__ W1pT,
    const __bf16* __restrict__ WabT, const __bf16* __restrict__ WdT,
    const __bf16* __restrict__ WcT, const __bf16* __restrict__ WoT,
    const __bf16* __restrict__ Wo2T, const float* __restrict__ vecs,
    const float* __restrict__ out_b2, float* __restrict__ out)
{
  __shared__ __align__(16) char smem[38912];
  // X [0,17408): phases 0-1: featL bf16[64][FSTR] (9216 B). Phase 2+: Ab
  //   bf16[64][LROW] (A, then S in place).
  // Y [17408,34816): h1 bf16[64][LROW] (phases 1-2); Bb after D pass;
  //   Sph @17408 / hob @21760 (phases 5+).
  // dist f32[512] @34816; vec f32[512] @36864.
  __bf16* featL = (__bf16*)(smem);
  __bf16* Ab    = (__bf16*)(smem);
  __bf16* h1    = (__bf16*)(smem + 17408);
  __bf16* Bb    = (__bf16*)(smem + 17408);
  __bf16* Sph   = (__bf16*)(smem + 17408);
  __bf16* hob   = (__bf16*)(smem + 21760);
  float*  dist  = (float*)(smem + 34816);
  float*  vec   = (float*)(smem + 36864);

  const int tid  = threadIdx.x;
  const int lane = tid & 63;
  const int w    = tid >> 6;      // wave 0..3
  const int l15  = lane & 15;
  const int quad = lane >> 4;
  const int colw = w * 32;        // this wave's 32-col slice
  const int g0   = blockIdx.x * 8;
  const int n0   = blockIdx.x * 64;

  // ---- phase 0: build feature rows (thread-private: no race), dist, vec
  if (tid < 64) {
    uint4* rp = (uint4*)&featL[tid * FSTR];   // 144 B row, 16B-aligned
    uint4 z4 = {0u, 0u, 0u, 0u};
    #pragma unroll
    for (int i = 0; i < 9; ++i) rp[i] = z4;
    int g = tid >> 3;
    float px = positions[(n0 + tid) * 2], py = positions[(n0 + tid) * 2 + 1];
    int c  = colors[n0 + tid], mk = markers[n0 + tid] - 8;
    int a  = anchors[g0 + g],  nj = n_jumps[g0 + g];
    __bf16* row = &featL[tid * FSTR];
    row[0] = (__bf16)px; row[1] = (__bf16)py;
    const __bf16 one = (__bf16)1.f;
    row[2 + c] = one; row[10 + mk] = one;
    row[18 + a] = one; row[34 + nj] = one;
    row[42] = one;                              // bias-as-feature
  }
  for (int i = tid; i < 512; i += 256) {
    int g = i >> 6, ii = (i >> 3) & 7, jj = i & 7;
    const float* pa = positions + (n0 + g * 8 + ii) * 2;
    const float* pb = positions + (n0 + g * 8 + jj) * 2;
    float dx = pa[0] - pb[0], dy = pa[1] - pb[1];
    dist[i] = sqrtf(dx * dx + dy * dy);
  }
  for (int i = tid; i < 512; i += 256) vec[i] = vecs[i];
  __syncthreads();

  // ---- phase 1: h1 = relu(featL @ W1pT) via MFMA (M=64, N=128, K=64 padded)
  {
    f32x4 acch[4][2];
    f32x4 zero = {0.f, 0.f, 0.f, 0.f};
    #pragma unroll
    for (int mt = 0; mt < 4; ++mt) { acch[mt][0] = zero; acch[mt][1] = zero; }
    #pragma unroll
    for (int kb = 0; kb < 64; kb += 32) {
      const int ko = kb + quad * 8;
      bf16x8 fa[4], fb[2];
      #pragma unroll
      for (int mt = 0; mt < 4; ++mt)
        fa[mt] = *(const bf16x8*)&featL[(mt * 16 + l15) * FSTR + ko];
      fb[0] = *(const bf16x8*)&W1pT[(colw + l15) * 64 + ko];
      fb[1] = *(const bf16x8*)&W1pT[(colw + 16 + l15) * 64 + ko];
      #pragma unroll
      for (int mt = 0; mt < 4; ++mt) {
        acch[mt][0] = MFMA16(fa[mt], fb[0], acch[mt][0]);
        acch[mt][1] = MFMA16(fa[mt], fb[1], acch[mt][1]);
      }
    }
    __syncthreads();   // ensure all waves finished reading featL before... (see note)
    // note: h1 lives in Y (disjoint from featL in X), so the only hazard is
    // phase-2's A write into X -- which happens after the post-phase-1 barrier.
    #pragma unroll
    for (int mt = 0; mt < 4; ++mt)
      #pragma unroll
      for (int nt = 0; nt < 2; ++nt) {
        int col = colw + nt * 16 + l15;
        #pragma unroll
        for (int r = 0; r < 4; ++r)
          h1[(mt * 16 + quad * 4 + r) * LROW + col] = (__bf16)fmaxf(acch[mt][nt][r], 0.f);
      }
  }
  __syncthreads();

  // ---- phase 2 pass 1: [A|B] cols colw..colw+31 = h1 @ WabT (16 accs)
  f32x4 acc1[4][4];   // nt 0,1 -> A; nt 2,3 -> B
  {
    f32x4 zero = {0.f, 0.f, 0.f, 0.f};
    #pragma unroll
    for (int mt = 0; mt < 4; ++mt)
      #pragma unroll
      for (int nt = 0; nt < 4; ++nt) acc1[mt][nt] = zero;
  }
  #pragma unroll
  for (int kb = 0; kb < 128; kb += 32) {
    const int ko = kb + quad * 8;
    bf16x8 fa[4], fb[4];
    #pragma unroll
    for (int mt = 0; mt < 4; ++mt)
      fa[mt] = *(const bf16x8*)&h1[(mt * 16 + l15) * LROW + ko];
    fb[0] = *(const bf16x8*)&WabT[(colw + l15) * 128 + ko];
    fb[1] = *(const bf16x8*)&WabT[(colw + 16 + l15) * 128 + ko];
    fb[2] = *(const bf16x8*)&WabT[(128 + colw + l15) * 128 + ko];
    fb[3] = *(const bf16x8*)&WabT[(128 + colw + 16 + l15) * 128 + ko];
    #pragma unroll
    for (int mt = 0; mt < 4; ++mt)
      #pragma unroll
      for (int nt = 0; nt < 4; ++nt)
        acc1[mt][nt] = MFMA16(fa[mt], fb[nt], acc1[mt][nt]);
  }
  // write back A now (featL dead since post-phase-1 barrier)
  #pragma unroll
  for (int mt = 0; mt < 4; ++mt)
    #pragma unroll
    for (int nt = 0; nt < 2; ++nt) {
      int col = colw + nt * 16 + l15;
      #pragma unroll
      for (int r = 0; r < 4; ++r)
        Ab[(mt * 16 + quad * 4 + r) * LROW + col] = (__bf16)acc1[mt][nt][r];
    }

  // ---- phase 2 pass 2: D cols colw..colw+31 = h1 @ WdT (8 accs, live to phase 5)
  f32x4 accD[4][2];
  {
    f32x4 zero = {0.f, 0.f, 0.f, 0.f};
    #pragma unroll
    for (int mt = 0; mt < 4; ++mt) { accD[mt][0] = zero; accD[mt][1] = zero; }
  }
  #pragma unroll
  for (int kb = 0; kb < 128; kb += 32) {
    const int ko = kb + quad * 8;
    bf16x8 fa[4], fd[2];
    #pragma unroll
    for (int mt = 0; mt < 4; ++mt)
      fa[mt] = *(const bf16x8*)&h1[(mt * 16 + l15) * LROW + ko];
    fd[0] = *(const bf16x8*)&WdT[(colw + l15) * 128 + ko];
    fd[1] = *(const bf16x8*)&WdT[(colw + 16 + l15) * 128 + ko];
    #pragma unroll
    for (int mt = 0; mt < 4; ++mt) {
      accD[mt][0] = MFMA16(fa[mt], fd[0], accD[mt][0]);
      accD[mt][1] = MFMA16(fa[mt], fd[1], accD[mt][1]);
    }
  }
  __syncthreads();   // all waves done reading h1
  // write back B over the dead h1 region
  #pragma unroll
  for (int mt = 0; mt < 4; ++mt)
    #pragma unroll
    for (int nt = 2; nt < 4; ++nt) {
      int col = colw + (nt - 2) * 16 + l15;
      #pragma unroll
      for (int r = 0; r < 4; ++r)
        Bb[(mt * 16 + quad * 4 + r) * LROW + col] = (__bf16)acc1[mt][nt][r];
    }
  __syncthreads();

  // ---- phase 4: edges, packed f32x2. S[i] = sum_{j!=i} relu(A[i]+B[j]+d_ij*w1d+cAB).
  //      S overwrites A in-place (each thread owns its (row, 4-col) slice).
  {
    const int g   = tid >> 5;          // graph 0..7
    const int nb4 = (tid & 31) * 4;    // 4 hidden dims per thread (2 f32x2 pairs)
    const f32x2 w0 = *(const f32x2*)&vec[nb4];
    const f32x2 w1 = *(const f32x2*)&vec[nb4 + 2];
    const f32x2 c0 = *(const f32x2*)&vec[128 + nb4];
    const f32x2 c1 = *(const f32x2*)&vec[128 + nb4 + 2];
    const f32x2 z2 = {0.f, 0.f};
    f32x2 B0[8], B1[8];
    #pragma unroll
    for (int j = 0; j < 8; ++j) {
      uint2 vb = *(const uint2*)&Bb[(g * 8 + j) * LROW + nb4];
      B0[j].x = bflo(vb.x); B0[j].y = bfhi(vb.x);
      B1[j].x = bflo(vb.y); B1[j].y = bfhi(vb.y);
    }
    #pragma unroll
    for (int i = 0; i < 8; ++i) {
      uint2 va = *(const uint2*)&Ab[(g * 8 + i) * LROW + nb4];
      f32x2 a0; a0.x = bflo(va.x); a0.y = bfhi(va.x); a0 += c0;
      f32x2 a1; a1.x = bflo(va.y); a1.y = bfhi(va.y); a1 += c1;
      f32x2 s0 = z2, s1 = z2;
      #pragma unroll
      for (int j = 0; j < 8; ++j) {
        if (j == i) continue;
        float d = dist[g * 64 + i * 8 + j];
        f32x2 d2 = {d, d};
        f32x2 t0 = __builtin_elementwise_fma(d2, w0, B0[j]) + a0;
        f32x2 t1 = __builtin_elementwise_fma(d2, w1, B1[j]) + a1;
        t0 = __builtin_elementwise_max(t0, z2);
        t1 = __builtin_elementwise_max(t1, z2);
        s0 += t0; s1 += t1;
      }
      unsigned o0 = (unsigned)f2bf_u16(s0.x) | ((unsigned)f2bf_u16(s0.y) << 16);
      unsigned o1 = (unsigned)f2bf_u16(s1.x) | ((unsigned)f2bf_u16(s1.y) << 16);
      uint2 o = {o0, o1};
      *(uint2*)&Ab[(g * 8 + i) * LROW + nb4] = o;   // in-place
    }
  }
  __syncthreads();

  // ---- phase 5: ph = relu(S@Wc + D + cP); per-graph sum -> Sph (pad rows zeroed)
  {
    const __bf16* Sb = Ab;
    #pragma unroll
    for (int kb = 0; kb < 128; kb += 32) {
      const int ko = kb + quad * 8;
      bf16x8 fa[4], fc[2];
      #pragma unroll
      for (int mt = 0; mt < 4; ++mt)
        fa[mt] = *(const bf16x8*)&Sb[(mt * 16 + l15) * LROW + ko];
      fc[0] = *(const bf16x8*)&WcT[(colw + l15) * 128 + ko];
      fc[1] = *(const bf16x8*)&WcT[(colw + 16 + l15) * 128 + ko];
      #pragma unroll
      for (int mt = 0; mt < 4; ++mt) {
        accD[mt][0] = MFMA16(fa[mt], fc[0], accD[mt][0]);
        accD[mt][1] = MFMA16(fa[mt], fc[1], accD[mt][1]);
      }
    }
    #pragma unroll
    for (int mt = 0; mt < 4; ++mt)
      #pragma unroll
      for (int dt = 0; dt < 2; ++dt) {
        int col = colw + dt * 16 + l15;
        float cp = vec[256 + col];
        f32x4 a = accD[mt][dt];
        float s = fmaxf(a[0] + cp, 0.f) + fmaxf(a[1] + cp, 0.f)
                + fmaxf(a[2] + cp, 0.f) + fmaxf(a[3] + cp, 0.f);
        s += __shfl_xor(s, 16);
        int grow = mt * 2 + (lane >= 32 ? 1 : 0);
        if ((lane & 31) < 16) Sph[grow * LROW + col] = (__bf16)s;
        else                  Sph[(8 + grow) * LROW + col] = (__bf16)0.f;
      }
  }
  __syncthreads();

  // ---- phase 6: ho = relu(Sph @ WO + cO)  (M=16 tile: 8 graphs + 8 zero rows)
  {
    f32x4 acco[2];
    f32x4 zero = {0.f, 0.f, 0.f, 0.f};
    acco[0] = zero; acco[1] = zero;
    #pragma unroll
    for (int kb = 0; kb < 128; kb += 32) {
      const int ko = kb + quad * 8;
      bf16x8 fa = *(const bf16x8*)&Sph[l15 * LROW + ko];
      bf16x8 fb0 = *(const bf16x8*)&WoT[(colw + l15) * 128 + ko];
      bf16x8 fb1 = *(const bf16x8*)&WoT[(colw + 16 + l15) * 128 + ko];
      acco[0] = MFMA16(fa, fb0, acco[0]);
      acco[1] = MFMA16(fa, fb1, acco[1]);
    }
    #pragma unroll
    for (int dt = 0; dt < 2; ++dt) {
      int col = colw + dt * 16 + l15;
      float co = vec[384 + col];
      #pragma unroll
      for (int r = 0; r < 4; ++r)
        hob[(quad * 4 + r) * LROW + col] = (__bf16)fmaxf(acco[dt][r] + co, 0.f);
    }
  }
  __syncthreads();

  // ---- phase 7: logits = ho @ out_W2 + out_b2  (wave 0 only)
  if (w == 0) {
    f32x4 accf = {0.f, 0.f, 0.f, 0.f};
    #pragma unroll
    for (int kb = 0; kb < 128; kb += 32) {
      const int ko = kb + quad * 8;
      bf16x8 fa  = *(const bf16x8*)&hob[l15 * LROW + ko];
      bf16x8 fbv = *(const bf16x8*)&Wo2T[l15 * 128 + ko];
      accf = MFMA16(fa, fbv, accf);
    }
    if (quad < 2) {
      float b2 = out_b2[l15];
      #pragma unroll
      for (int r = 0; r < 4; ++r) {
        int row = quad * 4 + r;
        out[(g0 + row) * 16 + l15] = accf[r] + b2;
      }
    }
  }
}

extern "C" void kernel_launch(void* const* d_in, const int* in_sizes, int n_in,
                              void* d_out, int out_size, void* d_ws, size_t ws_size,
                              hipStream_t stream) {
  const int*   anchors   = (const int*)d_in[0];
  const int*   n_jumps   = (const int*)d_in[1];
  const float* positions = (const float*)d_in[2];
  const int*   colors    = (const int*)d_in[3];
  const int*   markers   = (const int*)d_in[4];
  const float* pre_W1  = (const float*)d_in[5];
  const float* pre_b1  = (const float*)d_in[6];
  const float* pre_W2  = (const float*)d_in[7];
  const float* pre_b2  = (const float*)d_in[8];
  const float* msg_W1  = (const float*)d_in[9];
  const float* msg_b1  = (const float*)d_in[10];
  const float* msg_W2  = (const float*)d_in[11];
  const float* msg_b2  = (const float*)d_in[12];
  const float* post_W1 = (const float*)d_in[13];
  const float* post_b1 = (const float*)d_in[14];
  const float* post_W2 = (const float*)d_in[15];
  const float* post_b2 = (const float*)d_in[16];
  const float* out_W1  = (const float*)d_in[17];
  const float* out_b1  = (const float*)d_in[18];
  const float* out_W2  = (const float*)d_in[19];
  const float* out_b2  = (const float*)d_in[20];

  char* ws = (char*)d_ws;
  unsigned short* WabT = (unsigned short*)(ws);            // [256][128] bf16
  unsigned short* WdT  = (unsigned short*)(ws + 65536);    // [128][128]
  unsigned short* WcT  = (unsigned short*)(ws + 98304);    // [128][128]
  unsigned short* WoT  = (unsigned short*)(ws + 131072);   // [128][128]
  unsigned short* Wo2T = (unsigned short*)(ws + 163840);   // [16][128]
  float*          vecs = (float*)(ws + 167936);            // 512 f32
  unsigned short* W1pT = (unsigned short*)(ws + 169984);   // [128][64] bf16

  const int BS = in_sizes[0];

  combine_weights<<<324, 256, 0, stream>>>(
      pre_W1, pre_b1, pre_W2, msg_W1, msg_W2, post_W1, post_W2, out_W1, out_W2,
      pre_b2, msg_b1, msg_b2, post_b1, post_b2, out_b1,
      WabT, WdT, WcT, WoT, Wo2T, W1pT, vecs);

  rrn_main<<<BS / 8, 256, 0, stream>>>(
      anchors, n_jumps, positions, colors, markers,
      (const __bf16*)W1pT,
      (const __bf16*)WabT, (const __bf16*)WdT, (const __bf16*)WcT,
      (const __bf16*)WoT, (const __bf16*)Wo2T, vecs, out_b2, (float*)d_out);
}